// Round 13
// baseline (171.296 us; speedup 1.0000x reference)
//
#include <hip/hip_runtime.h>
#include <math.h>

#define BB 8
#define E  128
#define OO 256
#define HH 112
#define WW 112
#define HWP (HH*WW)   // 12544

typedef _Float16 f16;
typedef _Float16 half8 __attribute__((ext_vector_type(8)));
typedef float f32x4 __attribute__((ext_vector_type(4)));

// R4-proven swizzle for 64B-stride (32 f16) rows
#define SWZ(q, c) ((((q) + ((c) >> 1)) & 3) * 8)

// direct global->LDS DMA, 16B per lane; LDS dest is wave-uniform base + lane*16
__device__ __forceinline__ void load_lds16(const f16* g, f16* l) {
    __builtin_amdgcn_global_load_lds(
        (const __attribute__((address_space(1))) void*)g,
        (__attribute__((address_space(3))) void*)l, 16, 0, 0);
}

// ---------------- precompute 1: normalized f16 weights [tap][o][ch] + zero page
__global__ __launch_bounds__(128)
void wnorm16z_kernel(const float* __restrict__ wgt, f16* __restrict__ wn16,
                     float* __restrict__ zp) {
    if (blockIdx.x == 0 && threadIdx.x < 64) {
        float4 z = {0.f, 0.f, 0.f, 0.f};
        ((float4*)zp)[threadIdx.x] = z;     // 1KB zero page
    }
    int o = blockIdx.x;
    int c = threadIdx.x;
    const float* row = wgt + (size_t)o * 1152 + c * 9;
    float v[9];
    float ss = 0.f;
    #pragma unroll
    for (int tp = 0; tp < 9; ++tp) { v[tp] = row[tp]; ss = fmaf(v[tp], v[tp], ss); }
    ss += __shfl_xor(ss, 1);  ss += __shfl_xor(ss, 2);
    ss += __shfl_xor(ss, 4);  ss += __shfl_xor(ss, 8);
    ss += __shfl_xor(ss, 16); ss += __shfl_xor(ss, 32);
    __shared__ float r2[2];
    if ((c & 63) == 0) r2[c >> 6] = ss;
    __syncthreads();
    float inv = rsqrtf(fmaxf(r2[0] + r2[1], 1e-24f));
    #pragma unroll
    for (int tp = 0; tp < 9; ++tp)
        wn16[((size_t)tp * OO + o) * E + c] = (f16)(v[tp] * inv);
}

// ---------------- precompute 2a: x -> channel-last f16 xt[b][hw][c] + per-pixel ssq
__global__ __launch_bounds__(256)
void xcvt_kernel(const float* __restrict__ x, f16* __restrict__ xt,
                 float* __restrict__ ssq) {
    int blk = blockIdx.x;            // BB*49 blocks
    int b   = blk / 49;
    int hw  = (blk % 49) * 256 + threadIdx.x;
    const float* xb = x + (size_t)b * E * HWP + hw;
    f16* xo = xt + ((size_t)b * HWP + hw) * E;
    float s = 0.f;
    #pragma unroll 4
    for (int co = 0; co < 16; ++co) {
        half8 pk;
        #pragma unroll
        for (int e = 0; e < 8; ++e) {
            float v = xb[(size_t)(co * 8 + e) * HWP];   // coalesced across threads
            s = fmaf(v, v, s);
            pk[e] = (f16)v;
        }
        *(half8*)(xo + co * 8) = pk;
    }
    ssq[(size_t)b * HWP + hw] = s;
}

// ---------------- precompute 2b: 3x3 box-sum of ssq -> inverse patch norm
__global__ __launch_bounds__(256)
void boxinv2_kernel(const float* __restrict__ ssq, float* __restrict__ pinv) {
    int id = blockIdx.x * 256 + threadIdx.x;
    int b = id / HWP;
    int hw = id % HWP;
    int h = hw / WW, w = hw % WW;
    const float* sb = ssq + (size_t)b * HWP;
    float S = 0.f;
    #pragma unroll
    for (int r = -1; r <= 1; ++r) {
        int hh = h + r;
        if ((unsigned)hh >= HH) continue;
        #pragma unroll
        for (int c = -1; c <= 1; ++c) {
            int ww = w + c;
            if ((unsigned)ww >= WW) continue;
            S += sb[hh * WW + ww];
        }
    }
    pinv[id] = rsqrtf(fmaxf(S, 1e-24f));
}

// ---------------- tier-A main: chunk32, no pad, A from global/L2, xs dbuf gload_lds
// Block: 64 o x 2 h x 128 w; 4 waves; wave = 64o x 64px (m4 x n4, 16x16x32 f16).
__global__ __launch_bounds__(256, 2)
void cossim_ag(const f16* __restrict__ xt, const f16* __restrict__ wn16,
               const float* __restrict__ pinv, const f16* __restrict__ zp,
               float* __restrict__ out) {
    int bid = blockIdx.x;        // XCD-aware: b = bid&7
    int b   = bid & 7;
    int j2  = bid >> 3;
    int oy  = j2 / 56;
    int hp  = j2 % 56;
    int h0 = hp * 2;
    int o0 = oy * 64;
    int t    = threadIdx.x;
    int lane = t & 63;
    int wv   = t >> 6;
    const int lr = lane & 15;
    const int ls = lane >> 4;

    __shared__ f16 xsb[2][16896];   // 2112 slots x 16B (2080 used + pad)
    __shared__ f16 scr[1024];       // dummy-DMA landing zone

    // chunk-invariant staging source offsets (slot -> pre-swizzled global addr)
    int xoff[9];
    #pragma unroll
    for (int k = 0; k < 9; ++k) {
        int jj = k * 4 + wv;
        int s = jj * 64 + lane;
        int xo = -1;
        if (s < 2080) {
            int r = s / 520, rem = s - r * 520;
            int cs = rem >> 2, q = rem & 3;
            int qp = (q - (cs >> 1)) & 3;        // inverse of SWZ
            int gh = h0 - 1 + r, gw = cs - 1;
            if ((unsigned)gh < HH && (unsigned)gw < WW)
                xo = (gh * WW + gw) * E + qp * 8;
        }
        xoff[k] = xo;
    }
    const f16* xb = xt + (size_t)b * HWP * E;
    const f16* wl = wn16 + (size_t)(o0 + lr) * E + ls * 8;

    f32x4 acc[4][4] = {};
    half8 Af[12];

#define STAGE(CH0, BUF) do {                                                    \
    _Pragma("unroll")                                                           \
    for (int k_ = 0; k_ < 9; ++k_) {                                            \
        int jj_ = k_ * 4 + wv;                                                  \
        f16* dst_ = (jj_ < 33) ? &xsb[BUF][jj_ * 512] : scr;                    \
        const f16* src_ = (xoff[k_] >= 0) ? (xb + xoff[k_] + (CH0)) : zp;       \
        load_lds16(src_, dst_);                                                 \
    } } while (0)

#define LDAG(G, CH0) do {                                                       \
    _Pragma("unroll")                                                           \
    for (int tp_ = 0; tp_ < 3; ++tp_)                                           \
        _Pragma("unroll")                                                       \
        for (int mi_ = 0; mi_ < 4; ++mi_)                                       \
            Af[tp_ * 4 + mi_] = *(const half8*)(wl +                            \
                (size_t)((((G) * 3 + tp_) * OO + mi_ * 16)) * E + (CH0));       \
    } while (0)

#define TAPM(TAP, G, BUF) do {                                                  \
    half8 Bf[4];                                                                \
    {                                                                           \
        const int kh_ = (TAP) / 3, kw_ = (TAP) % 3;                             \
        _Pragma("unroll")                                                       \
        for (int dh_ = 0; dh_ < 2; ++dh_)                                       \
            _Pragma("unroll")                                                   \
            for (int wg_ = 0; wg_ < 2; ++wg_) {                                 \
                int col_ = wv * 32 + wg_ * 16 + lr + kw_;                       \
                Bf[dh_ * 2 + wg_] = *(const half8*)&xsb[BUF][                   \
                    (((dh_ + kh_) * 130 + col_) * 4 + ((ls + (col_ >> 1)) & 3)) * 8]; \
            }                                                                   \
    }                                                                           \
    _Pragma("unroll")                                                           \
    for (int mi_ = 0; mi_ < 4; ++mi_)                                           \
        _Pragma("unroll")                                                       \
        for (int ni_ = 0; ni_ < 4; ++ni_)                                       \
            acc[mi_][ni_] = __builtin_amdgcn_mfma_f32_16x16x32_f16(             \
                Af[((TAP) - (G) * 3) * 4 + mi_], Bf[ni_], acc[mi_][ni_], 0, 0, 0); \
    } while (0)

#define CHUNK(C, LAST) do {                                                     \
    LDAG(0, (C) * 32);                                                          \
    __builtin_amdgcn_sched_barrier(0);                                          \
    if (!(LAST)) STAGE((C) * 32 + 32, ((C) + 1) & 1);                           \
    __builtin_amdgcn_s_setprio(1);                                              \
    TAPM(0, 0, (C) & 1); TAPM(1, 0, (C) & 1); TAPM(2, 0, (C) & 1);              \
    LDAG(1, (C) * 32);                                                          \
    TAPM(3, 1, (C) & 1); TAPM(4, 1, (C) & 1); TAPM(5, 1, (C) & 1);              \
    LDAG(2, (C) * 32);                                                          \
    TAPM(6, 2, (C) & 1); TAPM(7, 2, (C) & 1); TAPM(8, 2, (C) & 1);              \
    __builtin_amdgcn_s_setprio(0);                                              \
    __syncthreads();   /* drains STAGE(c+1) (a full chunk old) + phase fence */ \
    } while (0)

    STAGE(0, 0);
    __syncthreads();
    CHUNK(0, 0);
    CHUNK(1, 0);
    CHUNK(2, 0);
    CHUNK(3, 1);

#undef STAGE
#undef LDAG
#undef TAPM
#undef CHUNK

    // epilogue: scale by pinv (weights pre-normalized)
    int lq = lane >> 4;
    #pragma unroll
    for (int ni = 0; ni < 4; ++ni) {
        int dh = ni >> 1, wsg = ni & 1;
        int w = wv * 32 + wsg * 16 + lr;
        if (w >= WW) continue;
        float pv = pinv[(size_t)b * HWP + (h0 + dh) * WW + w];
        int h = h0 + dh;
        #pragma unroll
        for (int mi = 0; mi < 4; ++mi) {
            #pragma unroll
            for (int rg = 0; rg < 4; ++rg) {
                int row = lq * 4 + rg;
                out[((size_t)(b * OO + o0 + mi * 16 + row)) * HWP + h * WW + w]
                    = acc[mi][ni][rg] * pv;
            }
        }
    }
}

// ---------------- fallback (R4-proven) main kernel
template<int FAST>
__global__ __launch_bounds__(256, 2)
void cossim_mfma(const float* __restrict__ x, const float* __restrict__ wgt,
                 const f16* __restrict__ wn16, float* __restrict__ out) {
    int hp = blockIdx.x;
    int oy = blockIdx.y;
    int b  = blockIdx.z;
    int h0 = hp * 2;
    int o0 = oy * 64;
    int t    = threadIdx.x;
    int lane = t & 63;
    int wv   = t >> 6;

    __shared__ f16   ws[9][64][32];
    __shared__ f16   xs[4][130][32];
    __shared__ float ssqAcc[4][130];
    __shared__ float wSsq[64];
    __shared__ float pinvL[2][128];
    __shared__ float winv[64];

    for (int i = t; i < 4*130 + 64; i += 256) {
        if (i < 4*130) ((float*)ssqAcc)[i] = 0.f;
        else wSsq[i - 4*130] = 0.f;
    }
    __syncthreads();

    f32x4 zero4 = {0.f, 0.f, 0.f, 0.f};
    f32x4 acc[4][4];
    #pragma unroll
    for (int mi = 0; mi < 4; ++mi)
        #pragma unroll
        for (int ni = 0; ni < 4; ++ni) acc[mi][ni] = zero4;

    const int lr = lane & 15;
    const int ls = lane >> 4;

    for (int ch0 = 0; ch0 < E; ch0 += 32) {
        if (FAST) {
            int o = t >> 2, q = t & 3;
            #pragma unroll
            for (int r = 0; r < 9; ++r) {
                half8 v = *(const half8*)(wn16 + ((size_t)(r * OO + o0 + o)) * E + ch0 + q * 8);
                *(half8*)&ws[r][o][SWZ(q, o)] = v;
            }
        } else {
            int o = t >> 2, q = t & 3;
            const float* wrow = wgt + (size_t)(o0 + o) * 1152 + ch0 * 9 + q * 72;
            float v[72];
            float ss = 0.f;
            #pragma unroll
            for (int i = 0; i < 18; ++i) {
                float4 f = ((const float4*)wrow)[i];
                v[i*4+0] = f.x; v[i*4+1] = f.y; v[i*4+2] = f.z; v[i*4+3] = f.w;
                ss = fmaf(f.x, f.x, ss); ss = fmaf(f.y, f.y, ss);
                ss = fmaf(f.z, f.z, ss); ss = fmaf(f.w, f.w, ss);
            }
            #pragma unroll
            for (int tp = 0; tp < 9; ++tp) {
                half8 pk;
                #pragma unroll
                for (int cl = 0; cl < 8; ++cl) pk[cl] = (f16)v[cl*9 + tp];
                *(half8*)&ws[tp][o][SWZ(q, o)] = pk;
            }
            ss += __shfl_xor(ss, 1);
            ss += __shfl_xor(ss, 2);
            if (q == 0) wSsq[o] += ss;
        }
        {
            int colL = lane & 15, cq = lane >> 4;
            #pragma unroll 2
            for (int it = 0; it < 9; ++it) {
                int g = it * 4 + wv;
                int r = g / 9, colb = g % 9;
                int cs = colb * 16 + colL;
                int gh = h0 - 1 + r;
                int gw = cs - 1;
                bool okc = (cs < 130);
                bool ok  = okc && ((unsigned)gh < HH) && ((unsigned)gw < WW);
                const float* xp = x + ((size_t)b * E + ch0 + cq * 8) * HWP + gh * WW + gw;
                float vv[8];
                float ss = 0.f;
                #pragma unroll
                for (int e = 0; e < 8; ++e) {
                    float v = ok ? xp[e * HWP] : 0.f;
                    vv[e] = v;
                    ss = fmaf(v, v, ss);
                }
                if (okc) {
                    half8 pk;
                    #pragma unroll
                    for (int e = 0; e < 8; ++e) pk[e] = (f16)vv[e];
                    *(half8*)&xs[r][cs][SWZ(cq, cs)] = pk;
                }
                ss += __shfl_xor(ss, 16);
                ss += __shfl_xor(ss, 32);
                if (cq == 0 && okc) ssqAcc[r][cs] += ss;
            }
        }
        __syncthreads();

        __builtin_amdgcn_s_setprio(1);
        #pragma unroll
        for (int tap = 0; tap < 9; ++tap) {
            int kh = tap / 3, kw = tap % 3;
            half8 A[4], Bf[4];
            #pragma unroll
            for (int mi = 0; mi < 4; ++mi) {
                int row = mi * 16 + lr;
                A[mi] = *(const half8*)&ws[tap][row][SWZ(ls, row)];
            }
            #pragma unroll
            for (int dh = 0; dh < 2; ++dh)
                #pragma unroll
                for (int wsg = 0; wsg < 2; ++wsg) {
                    int col = wv * 32 + wsg * 16 + lr + kw;
                    Bf[dh*2 + wsg] = *(const half8*)&xs[dh + kh][col][SWZ(ls, col)];
                }
            #pragma unroll
            for (int mi = 0; mi < 4; ++mi)
                #pragma unroll
                for (int ni = 0; ni < 4; ++ni)
                    acc[mi][ni] = __builtin_amdgcn_mfma_f32_16x16x32_f16(
                        A[mi], Bf[ni], acc[mi][ni], 0, 0, 0);
        }
        __builtin_amdgcn_s_setprio(0);
        __syncthreads();
    }

    if (!FAST && t < 64) winv[t] = rsqrtf(fmaxf(wSsq[t], 1e-24f));
    {
        int dh = t >> 7, w = t & 127;
        float S = 0.f;
        #pragma unroll
        for (int r = 0; r < 3; ++r)
            #pragma unroll
            for (int c = 0; c < 3; ++c)
                S += ssqAcc[dh + r][w + c];
        pinvL[dh][w] = rsqrtf(fmaxf(S, 1e-24f));
    }
    __syncthreads();

    int lq = lane >> 4;
    #pragma unroll
    for (int ni = 0; ni < 4; ++ni) {
        int dh = ni >> 1, wsg = ni & 1;
        int w = wv * 32 + wsg * 16 + lr;
        if (w >= WW) continue;
        float pv = pinvL[dh][w];
        int h = h0 + dh;
        #pragma unroll
        for (int mi = 0; mi < 4; ++mi) {
            #pragma unroll
            for (int rg = 0; rg < 4; ++rg) {
                int row = lq * 4 + rg;
                float s = acc[mi][ni][rg] * pv;
                if (!FAST) s *= winv[mi*16 + row];
                out[((size_t)(b * OO + o0 + mi*16 + row)) * HWP + h * WW + w] = s;
            }
        }
    }
}

extern "C" void kernel_launch(void* const* d_in, const int* in_sizes, int n_in,
                              void* d_out, int out_size, void* d_ws, size_t ws_size,
                              hipStream_t stream) {
    const float* x   = (const float*)d_in[0];
    const float* wgt = (const float*)d_in[1];
    float* out = (float*)d_out;

    const size_t zp_b   = 1024;
    const size_t xt_b   = (size_t)BB * HWP * E * sizeof(f16);        // 25,690,112
    const size_t ssq_b  = (size_t)BB * HWP * sizeof(float);          // 401,408
    const size_t pinv_b = (size_t)BB * HWP * sizeof(float);          // 401,408
    const size_t wn_b   = (size_t)9 * OO * E * sizeof(f16);          // 589,824
    const size_t need_A = zp_b + xt_b + ssq_b + pinv_b + wn_b;       // 27,083,776

    if (ws_size >= need_A && d_ws != nullptr) {
        f16*   zp   = (f16*)d_ws;
        f16*   xtp  = (f16*)((char*)d_ws + zp_b);
        float* ssq  = (float*)((char*)d_ws + zp_b + xt_b);
        float* pinv = (float*)((char*)d_ws + zp_b + xt_b + ssq_b);
        f16*   wn16 = (f16*)((char*)d_ws + zp_b + xt_b + ssq_b + pinv_b);
        xcvt_kernel    <<<BB * (HWP / 256), 256, 0, stream>>>(x, xtp, ssq);
        wnorm16z_kernel<<<OO, 128, 0, stream>>>(wgt, wn16, (float*)zp);
        boxinv2_kernel <<<BB * (HWP / 256), 256, 0, stream>>>(ssq, pinv);
        cossim_ag      <<<1792, 256, 0, stream>>>(xtp, wn16, pinv, zp, out);
    } else if (ws_size >= wn_b + zp_b && d_ws != nullptr) {
        f16*   wn16 = (f16*)d_ws;
        float* zp   = (float*)((char*)d_ws + wn_b);   // after wn16: no aliasing
        wnorm16z_kernel<<<OO, 128, 0, stream>>>(wgt, wn16, zp);
        cossim_mfma<1><<<dim3(56, 4, BB), 256, 0, stream>>>(x, wgt, wn16, out);
    } else {
        cossim_mfma<0><<<dim3(56, 4, BB), 256, 0, stream>>>(x, wgt, nullptr, out);
    }
}

// Round 14
// 139.307 us; speedup vs baseline: 1.2296x; 1.2296x over previous
//
#include <hip/hip_runtime.h>
#include <math.h>

#define BB 8
#define E  128
#define OO 256
#define HH 112
#define WW 112
#define HWP (HH*WW)   // 12544

typedef _Float16 f16;
typedef _Float16 half8 __attribute__((ext_vector_type(8)));
typedef float f32x4 __attribute__((ext_vector_type(4)));

// R4-proven swizzle for 64B-stride (32 f16) rows (fallback kernel)
#define SWZ(q, c) ((((q) + ((c) >> 1)) & 3) * 8)

// direct global->LDS DMA, 16B per lane
__device__ __forceinline__ void load_lds16(const f16* g, f16* l) {
    __builtin_amdgcn_global_load_lds(
        (const __attribute__((address_space(1))) void*)g,
        (__attribute__((address_space(3))) void*)l, 16, 0, 0);
}

// ---------------- precompute 1: normalized f16 weights [tap][o][ch] + zero page
__global__ __launch_bounds__(128)
void wnorm16z_kernel(const float* __restrict__ wgt, f16* __restrict__ wn16,
                     float* __restrict__ zp) {
    if (blockIdx.x == 0 && threadIdx.x < 64) {
        float4 z = {0.f, 0.f, 0.f, 0.f};
        ((float4*)zp)[threadIdx.x] = z;     // 1KB zero page
    }
    int o = blockIdx.x;
    int c = threadIdx.x;
    const float* row = wgt + (size_t)o * 1152 + c * 9;
    float v[9];
    float ss = 0.f;
    #pragma unroll
    for (int tp = 0; tp < 9; ++tp) { v[tp] = row[tp]; ss = fmaf(v[tp], v[tp], ss); }
    ss += __shfl_xor(ss, 1);  ss += __shfl_xor(ss, 2);
    ss += __shfl_xor(ss, 4);  ss += __shfl_xor(ss, 8);
    ss += __shfl_xor(ss, 16); ss += __shfl_xor(ss, 32);
    __shared__ float r2[2];
    if ((c & 63) == 0) r2[c >> 6] = ss;
    __syncthreads();
    float inv = rsqrtf(fmaxf(r2[0] + r2[1], 1e-24f));
    #pragma unroll
    for (int tp = 0; tp < 9; ++tp)
        wn16[((size_t)tp * OO + o) * E + c] = (f16)(v[tp] * inv);
}

// ---------------- precompute 2a: x -> channel-last f16 xt[b][hw][c] + per-pixel ssq
__global__ __launch_bounds__(256)
void xcvt_kernel(const float* __restrict__ x, f16* __restrict__ xt,
                 float* __restrict__ ssq) {
    int blk = blockIdx.x;            // BB*49 blocks
    int b   = blk / 49;
    int hw  = (blk % 49) * 256 + threadIdx.x;
    const float* xb = x + (size_t)b * E * HWP + hw;
    f16* xo = xt + ((size_t)b * HWP + hw) * E;
    float s = 0.f;
    #pragma unroll 4
    for (int co = 0; co < 16; ++co) {
        half8 pk;
        #pragma unroll
        for (int e = 0; e < 8; ++e) {
            float v = xb[(size_t)(co * 8 + e) * HWP];
            s = fmaf(v, v, s);
            pk[e] = (f16)v;
        }
        *(half8*)(xo + co * 8) = pk;
    }
    ssq[(size_t)b * HWP + hw] = s;
}

// ---------------- precompute 2b: 3x3 box-sum of ssq -> inverse patch norm
__global__ __launch_bounds__(256)
void boxinv2_kernel(const float* __restrict__ ssq, float* __restrict__ pinv) {
    int id = blockIdx.x * 256 + threadIdx.x;
    int b = id / HWP;
    int hw = id % HWP;
    int h = hw / WW, w = hw % WW;
    const float* sb = ssq + (size_t)b * HWP;
    float S = 0.f;
    #pragma unroll
    for (int r = -1; r <= 1; ++r) {
        int hh = h + r;
        if ((unsigned)hh >= HH) continue;
        #pragma unroll
        for (int c = -1; c <= 1; ++c) {
            int ww = w + c;
            if ((unsigned)ww >= WW) continue;
            S += sb[hh * WW + ww];
        }
    }
    pinv[id] = rsqrtf(fmaxf(S, 1e-24f));
}

// ---------------- tier-A main: m8n4 wave tile (128o x 64px), chunk16 tap-pairs.
// Block: 128 o x 2 h x 128 w; 4 waves. ws single-buffered (40KB) with T14
// reg-staged write; xs double-buffered via global_load_lds (R10-proven path).
__global__ __launch_bounds__(256, 1)
void cossim_m8(const f16* __restrict__ xt, const f16* __restrict__ wn16,
               const float* __restrict__ pinv, const f16* __restrict__ zp,
               float* __restrict__ out) {
    int bid = blockIdx.x;        // 0..895; XCD-aware: b = bid&7
    int b   = bid & 7;
    int j2  = bid >> 3;          // 0..111
    int oy  = j2 / 56;           // 0..1
    int hp  = j2 % 56;
    int h0 = hp * 2;
    int o0 = oy * 128;
    int t    = threadIdx.x;
    int lane = t & 63;
    int wv   = t >> 6;
    const int lr = lane & 15;
    const int ls = lane >> 4;

    __shared__ f16 xsb[2][8704];    // x dbuf: 1088 16B-slots each (1040 used)
    __shared__ f16 wsb[20480];      // ws single: [10 taps][128 o][2 oct] 16B-slots
    __shared__ f16 scr[512];        // dummy-DMA landing zone

    // zero pad-tap9 region of wsb (slots 2304..2559), written once
    {
        uint4 z = {0u, 0u, 0u, 0u};
        *(uint4*)&wsb[(2304 + t) * 8] = z;
    }

    // x staging source offsets (chunk-invariant; R10-proven decode)
    int xoff[5];
    #pragma unroll
    for (int k = 0; k < 5; ++k) {
        int jj = k * 4 + wv;
        int xo = -1;
        if (jj <= 16) {
            int s = jj * 64 + lane;
            if (s < 1040) {
                int po = s & 1, csm = s >> 1;
                int r = csm / 130, cs = csm - r * 130;
                int oct = po ^ ((cs >> 2) & 1);      // inverse swizzle
                int gh = h0 - 1 + r, gw = cs - 1;
                if ((unsigned)gh < (unsigned)HH && (unsigned)gw < (unsigned)WW)
                    xo = (gh * WW + gw) * E + oct * 8;
            }
        }
        xoff[k] = xo;
    }
    const f16* xb = xt + (size_t)b * HWP * E;

    // weight reg-stage source: thread t handles slots k*256+t -> (tap=k, o=t>>1, oct=t&1)
    const int wo  = t >> 1;
    const int wop = t & 1;
    const int wol = wop ^ ((wo >> 2) & 1);           // logical octet (inverse swizzle)
    const f16* wsrc = wn16 + (size_t)(o0 + wo) * E + wol * 8;

    f32x4 acc[8][4] = {};
    half8 wreg[9];

#define LOADW(CH0) do {                                                         \
    _Pragma("unroll")                                                           \
    for (int k_ = 0; k_ < 9; ++k_)                                              \
        wreg[k_] = *(const half8*)(wsrc + (size_t)(k_ * OO) * E + (CH0));       \
    } while (0)

#define WSWRITE() do {                                                          \
    _Pragma("unroll")                                                           \
    for (int k_ = 0; k_ < 9; ++k_)                                              \
        *(half8*)&wsb[(k_ * 256 + t) * 8] = wreg[k_];                           \
    } while (0)

#define STAGEX(CH0, BUF) do {                                                   \
    _Pragma("unroll")                                                           \
    for (int k_ = 0; k_ < 5; ++k_) {                                            \
        int jj_ = k_ * 4 + wv;                                                  \
        f16* dst_ = (jj_ <= 16) ? &xsb[BUF][jj_ * 512] : scr;                   \
        const f16* src_ = (xoff[k_] >= 0 && jj_ <= 16) ? (xb + xoff[k_] + (CH0)) : zp; \
        load_lds16(src_, dst_);                                                 \
    } } while (0)

#define MFMAP(BUF) do {                                                         \
    __builtin_amdgcn_s_setprio(1);                                              \
    _Pragma("unroll")                                                           \
    for (int p = 0; p < 5; ++p) {                                               \
        int tpl = 2 * p + (ls >> 1);                                            \
        int tpe = (tpl > 8) ? 0 : tpl;                                          \
        int kh = tpe / 3, kw = tpe - 3 * kh;                                    \
        int oct = ls & 1;                                                       \
        half8 A[8], Bf[4];                                                      \
        _Pragma("unroll")                                                       \
        for (int mi = 0; mi < 8; ++mi) {                                        \
            int row = mi * 16 + lr;                                             \
            A[mi] = *(const half8*)&wsb[                                        \
                (tpl * 256 + row * 2 + (oct ^ ((row >> 2) & 1))) * 8];          \
        }                                                                       \
        _Pragma("unroll")                                                       \
        for (int dh = 0; dh < 2; ++dh)                                          \
            _Pragma("unroll")                                                   \
            for (int wsg = 0; wsg < 2; ++wsg) {                                 \
                int col = wv * 32 + wsg * 16 + lr + kw;                         \
                Bf[dh * 2 + wsg] = *(const half8*)&xsb[BUF][                    \
                    ((dh + kh) * 260 + col * 2 + (oct ^ ((col >> 2) & 1))) * 8];\
            }                                                                   \
        _Pragma("unroll")                                                       \
        for (int mi = 0; mi < 8; ++mi)                                          \
            _Pragma("unroll")                                                   \
            for (int ni = 0; ni < 4; ++ni)                                      \
                acc[mi][ni] = __builtin_amdgcn_mfma_f32_16x16x32_f16(           \
                    A[mi], Bf[ni], acc[mi][ni], 0, 0, 0);                       \
    }                                                                           \
    __builtin_amdgcn_s_setprio(0);                                              \
} while (0)

#define RAWBAR() do {                                                           \
    __builtin_amdgcn_sched_barrier(0);                                          \
    __builtin_amdgcn_s_barrier();                                               \
    __builtin_amdgcn_sched_barrier(0);                                          \
} while (0)

#define DRAINBAR() do {                                                         \
    __builtin_amdgcn_sched_barrier(0);                                          \
    asm volatile("s_waitcnt vmcnt(0) lgkmcnt(0)" ::: "memory");                 \
    __builtin_amdgcn_s_barrier();                                               \
    __builtin_amdgcn_sched_barrier(0);                                          \
} while (0)

#define CHUNK(C, LAST) do {                                                     \
    if (!(LAST)) {                                                              \
        LOADW(((C) + 1) * 16);                                                  \
        STAGEX(((C) + 1) * 16, ((C) + 1) & 1);                                  \
    }                                                                           \
    MFMAP((C) & 1);                                                             \
    if (!(LAST)) {                                                              \
        RAWBAR();            /* all waves done reading wsb for chunk C */       \
        WSWRITE();           /* compiler waits wregs (vmcnt 5), xs flies */     \
        DRAINBAR();          /* xs DMA + ws writes visible to all */            \
    }                                                                           \
} while (0)

    // prologue: stage chunk 0 (ws via regs, xs via DMA)
    LOADW(0);
    WSWRITE();
    STAGEX(0, 0);
    DRAINBAR();

    CHUNK(0, 0); CHUNK(1, 0); CHUNK(2, 0); CHUNK(3, 0);
    CHUNK(4, 0); CHUNK(5, 0); CHUNK(6, 0); CHUNK(7, 1);

#undef LOADW
#undef WSWRITE
#undef STAGEX
#undef MFMAP
#undef RAWBAR
#undef DRAINBAR
#undef CHUNK

    // epilogue: scale by pinv (weights pre-normalized)
    int lq = lane >> 4;
    #pragma unroll
    for (int ni = 0; ni < 4; ++ni) {
        int dh = ni >> 1, wsg = ni & 1;
        int w = wv * 32 + wsg * 16 + lr;
        if (w >= WW) continue;
        float pv = pinv[(size_t)b * HWP + (h0 + dh) * WW + w];
        int h = h0 + dh;
        #pragma unroll
        for (int mi = 0; mi < 8; ++mi) {
            #pragma unroll
            for (int rg = 0; rg < 4; ++rg) {
                int row = lq * 4 + rg;
                out[((size_t)(b * OO + o0 + mi * 16 + row)) * HWP + h * WW + w]
                    = acc[mi][ni][rg] * pv;
            }
        }
    }
}

// ---------------- fallback (R4-proven) main kernel
template<int FAST>
__global__ __launch_bounds__(256, 2)
void cossim_mfma(const float* __restrict__ x, const float* __restrict__ wgt,
                 const f16* __restrict__ wn16, float* __restrict__ out) {
    int hp = blockIdx.x;
    int oy = blockIdx.y;
    int b  = blockIdx.z;
    int h0 = hp * 2;
    int o0 = oy * 64;
    int t    = threadIdx.x;
    int lane = t & 63;
    int wv   = t >> 6;

    __shared__ f16   ws[9][64][32];
    __shared__ f16   xs[4][130][32];
    __shared__ float ssqAcc[4][130];
    __shared__ float wSsq[64];
    __shared__ float pinvL[2][128];
    __shared__ float winv[64];

    for (int i = t; i < 4*130 + 64; i += 256) {
        if (i < 4*130) ((float*)ssqAcc)[i] = 0.f;
        else wSsq[i - 4*130] = 0.f;
    }
    __syncthreads();

    f32x4 zero4 = {0.f, 0.f, 0.f, 0.f};
    f32x4 acc[4][4];
    #pragma unroll
    for (int mi = 0; mi < 4; ++mi)
        #pragma unroll
        for (int ni = 0; ni < 4; ++ni) acc[mi][ni] = zero4;

    const int lr = lane & 15;
    const int ls = lane >> 4;

    for (int ch0 = 0; ch0 < E; ch0 += 32) {
        if (FAST) {
            int o = t >> 2, q = t & 3;
            #pragma unroll
            for (int r = 0; r < 9; ++r) {
                half8 v = *(const half8*)(wn16 + ((size_t)(r * OO + o0 + o)) * E + ch0 + q * 8);
                *(half8*)&ws[r][o][SWZ(q, o)] = v;
            }
        } else {
            int o = t >> 2, q = t & 3;
            const float* wrow = wgt + (size_t)(o0 + o) * 1152 + ch0 * 9 + q * 72;
            float v[72];
            float ss = 0.f;
            #pragma unroll
            for (int i = 0; i < 18; ++i) {
                float4 f = ((const float4*)wrow)[i];
                v[i*4+0] = f.x; v[i*4+1] = f.y; v[i*4+2] = f.z; v[i*4+3] = f.w;
                ss = fmaf(f.x, f.x, ss); ss = fmaf(f.y, f.y, ss);
                ss = fmaf(f.z, f.z, ss); ss = fmaf(f.w, f.w, ss);
            }
            #pragma unroll
            for (int tp = 0; tp < 9; ++tp) {
                half8 pk;
                #pragma unroll
                for (int cl = 0; cl < 8; ++cl) pk[cl] = (f16)v[cl*9 + tp];
                *(half8*)&ws[tp][o][SWZ(q, o)] = pk;
            }
            ss += __shfl_xor(ss, 1);
            ss += __shfl_xor(ss, 2);
            if (q == 0) wSsq[o] += ss;
        }
        {
            int colL = lane & 15, cq = lane >> 4;
            #pragma unroll 2
            for (int it = 0; it < 9; ++it) {
                int g = it * 4 + wv;
                int r = g / 9, colb = g % 9;
                int cs = colb * 16 + colL;
                int gh = h0 - 1 + r;
                int gw = cs - 1;
                bool okc = (cs < 130);
                bool ok  = okc && ((unsigned)gh < HH) && ((unsigned)gw < WW);
                const float* xp = x + ((size_t)b * E + ch0 + cq * 8) * HWP + gh * WW + gw;
                float vv[8];
                float ss = 0.f;
                #pragma unroll
                for (int e = 0; e < 8; ++e) {
                    float v = ok ? xp[e * HWP] : 0.f;
                    vv[e] = v;
                    ss = fmaf(v, v, ss);
                }
                if (okc) {
                    half8 pk;
                    #pragma unroll
                    for (int e = 0; e < 8; ++e) pk[e] = (f16)vv[e];
                    *(half8*)&xs[r][cs][SWZ(cq, cs)] = pk;
                }
                ss += __shfl_xor(ss, 16);
                ss += __shfl_xor(ss, 32);
                if (cq == 0 && okc) ssqAcc[r][cs] += ss;
            }
        }
        __syncthreads();

        __builtin_amdgcn_s_setprio(1);
        #pragma unroll
        for (int tap = 0; tap < 9; ++tap) {
            int kh = tap / 3, kw = tap % 3;
            half8 A[4], Bf[4];
            #pragma unroll
            for (int mi = 0; mi < 4; ++mi) {
                int row = mi * 16 + lr;
                A[mi] = *(const half8*)&ws[tap][row][SWZ(ls, row)];
            }
            #pragma unroll
            for (int dh = 0; dh < 2; ++dh)
                #pragma unroll
                for (int wsg = 0; wsg < 2; ++wsg) {
                    int col = wv * 32 + wsg * 16 + lr + kw;
                    Bf[dh*2 + wsg] = *(const half8*)&xs[dh + kh][col][SWZ(ls, col)];
                }
            #pragma unroll
            for (int mi = 0; mi < 4; ++mi)
                #pragma unroll
                for (int ni = 0; ni < 4; ++ni)
                    acc[mi][ni] = __builtin_amdgcn_mfma_f32_16x16x32_f16(
                        A[mi], Bf[ni], acc[mi][ni], 0, 0, 0);
        }
        __builtin_amdgcn_s_setprio(0);
        __syncthreads();
    }

    if (!FAST && t < 64) winv[t] = rsqrtf(fmaxf(wSsq[t], 1e-24f));
    {
        int dh = t >> 7, w = t & 127;
        float S = 0.f;
        #pragma unroll
        for (int r = 0; r < 3; ++r)
            #pragma unroll
            for (int c = 0; c < 3; ++c)
                S += ssqAcc[dh + r][w + c];
        pinvL[dh][w] = rsqrtf(fmaxf(S, 1e-24f));
    }
    __syncthreads();

    int lq = lane >> 4;
    #pragma unroll
    for (int ni = 0; ni < 4; ++ni) {
        int dh = ni >> 1, wsg = ni & 1;
        int w = wv * 32 + wsg * 16 + lr;
        if (w >= WW) continue;
        float pv = pinvL[dh][w];
        int h = h0 + dh;
        #pragma unroll
        for (int mi = 0; mi < 4; ++mi) {
            #pragma unroll
            for (int rg = 0; rg < 4; ++rg) {
                int row = lq * 4 + rg;
                float s = acc[mi][ni][rg] * pv;
                if (!FAST) s *= winv[mi*16 + row];
                out[((size_t)(b * OO + o0 + mi*16 + row)) * HWP + h * WW + w] = s;
            }
        }
    }
}

extern "C" void kernel_launch(void* const* d_in, const int* in_sizes, int n_in,
                              void* d_out, int out_size, void* d_ws, size_t ws_size,
                              hipStream_t stream) {
    const float* x   = (const float*)d_in[0];
    const float* wgt = (const float*)d_in[1];
    float* out = (float*)d_out;

    const size_t zp_b   = 1024;
    const size_t xt_b   = (size_t)BB * HWP * E * sizeof(f16);        // 25,690,112
    const size_t ssq_b  = (size_t)BB * HWP * sizeof(float);          // 401,408
    const size_t pinv_b = (size_t)BB * HWP * sizeof(float);          // 401,408
    const size_t wn_b   = (size_t)9 * OO * E * sizeof(f16);          // 589,824
    const size_t need_A = zp_b + xt_b + ssq_b + pinv_b + wn_b;       // 27,083,776

    if (ws_size >= need_A && d_ws != nullptr) {
        f16*   zp   = (f16*)d_ws;
        f16*   xtp  = (f16*)((char*)d_ws + zp_b);
        float* ssq  = (float*)((char*)d_ws + zp_b + xt_b);
        float* pinv = (float*)((char*)d_ws + zp_b + xt_b + ssq_b);
        f16*   wn16 = (f16*)((char*)d_ws + zp_b + xt_b + ssq_b + pinv_b);
        xcvt_kernel    <<<BB * (HWP / 256), 256, 0, stream>>>(x, xtp, ssq);
        wnorm16z_kernel<<<OO, 128, 0, stream>>>(wgt, wn16, (float*)zp);
        boxinv2_kernel <<<BB * (HWP / 256), 256, 0, stream>>>(ssq, pinv);
        cossim_m8      <<<896, 256, 0, stream>>>(xtp, wn16, pinv, zp, out);
    } else if (ws_size >= wn_b + zp_b && d_ws != nullptr) {
        f16*   wn16 = (f16*)d_ws;
        float* zp   = (float*)((char*)d_ws + wn_b);   // after wn16: no aliasing
        wnorm16z_kernel<<<OO, 128, 0, stream>>>(wgt, wn16, zp);
        cossim_mfma<1><<<dim3(56, 4, BB), 256, 0, stream>>>(x, wgt, wn16, out);
    } else {
        cossim_mfma<0><<<dim3(56, 4, BB), 256, 0, stream>>>(x, wgt, nullptr, out);
    }
}

// Round 15
// 89.386 us; speedup vs baseline: 1.9164x; 1.5585x over previous
//
#include <hip/hip_runtime.h>
#include <math.h>

#define BB 8
#define E  128
#define OO 256
#define HH 112
#define WW 112
#define HWP (HH*WW)   // 12544

typedef _Float16 f16;
typedef _Float16 half8 __attribute__((ext_vector_type(8)));
typedef float f32x4 __attribute__((ext_vector_type(4)));

// R4-proven swizzle for 64B-stride (32 f16) rows (fallback kernel)
#define SWZ(q, c) ((((q) + ((c) >> 1)) & 3) * 8)

// direct global->LDS DMA, 16B per lane; LDS dest is wave-uniform base + lane*16
__device__ __forceinline__ void load_lds16(const f16* g, f16* l) {
    __builtin_amdgcn_global_load_lds(
        (const __attribute__((address_space(1))) void*)g,
        (__attribute__((address_space(3))) void*)l, 16, 0, 0);
}

// ---------------- precompute 1 (tier-A): normalized f16 weights, [tap][cg][o][16] + zero page
__global__ __launch_bounds__(128)
void wnorm16b_kernel(const float* __restrict__ wgt, f16* __restrict__ wng,
                     float* __restrict__ zp) {
    if (blockIdx.x == 0 && threadIdx.x < 64) zp[threadIdx.x] = 0.f;   // 256B zero page
    int o = blockIdx.x;
    int c = threadIdx.x;
    const float* row = wgt + (size_t)o * 1152 + c * 9;
    float v[9];
    float ss = 0.f;
    #pragma unroll
    for (int tp = 0; tp < 9; ++tp) { v[tp] = row[tp]; ss = fmaf(v[tp], v[tp], ss); }
    ss += __shfl_xor(ss, 1);  ss += __shfl_xor(ss, 2);
    ss += __shfl_xor(ss, 4);  ss += __shfl_xor(ss, 8);
    ss += __shfl_xor(ss, 16); ss += __shfl_xor(ss, 32);
    __shared__ float r2[2];
    if ((c & 63) == 0) r2[c >> 6] = ss;
    __syncthreads();
    float inv = rsqrtf(fmaxf(r2[0] + r2[1], 1e-24f));
    int cg = c >> 4, ci = c & 15;
    #pragma unroll
    for (int tp = 0; tp < 9; ++tp)
        wng[(size_t)(tp * 8 + cg) * 4096 + o * 16 + ci] = (f16)(v[tp] * inv);
}

// ---------------- precompute 1 (fallback): normalized f16 weights, [tap][o][ch]
__global__ __launch_bounds__(128)
void wnorm16_kernel(const float* __restrict__ wgt, f16* __restrict__ wn16) {
    int o = blockIdx.x;
    int c = threadIdx.x;
    const float* row = wgt + (size_t)o * 1152 + c * 9;
    float v[9];
    float ss = 0.f;
    #pragma unroll
    for (int tp = 0; tp < 9; ++tp) { v[tp] = row[tp]; ss = fmaf(v[tp], v[tp], ss); }
    ss += __shfl_xor(ss, 1);  ss += __shfl_xor(ss, 2);
    ss += __shfl_xor(ss, 4);  ss += __shfl_xor(ss, 8);
    ss += __shfl_xor(ss, 16); ss += __shfl_xor(ss, 32);
    __shared__ float r2[2];
    if ((c & 63) == 0) r2[c >> 6] = ss;
    __syncthreads();
    float inv = rsqrtf(fmaxf(r2[0] + r2[1], 1e-24f));
    #pragma unroll
    for (int tp = 0; tp < 9; ++tp)
        wn16[((size_t)tp * OO + o) * E + c] = (f16)(v[tp] * inv);
}

// ---------------- precompute 2a: x -> f16 xt[b][cg][hw][16] + per-pixel ssq
__global__ __launch_bounds__(256)
void xcvt2_kernel(const float* __restrict__ x, f16* __restrict__ xtg,
                  float* __restrict__ ssq) {
    int blk = blockIdx.x;            // BB*49 blocks
    int b   = blk / 49;
    int hw  = (blk % 49) * 256 + threadIdx.x;
    const float* xb = x + (size_t)b * E * HWP + hw;
    float s = 0.f;
    #pragma unroll
    for (int cg = 0; cg < 8; ++cg) {
        half8 p0, p1;
        #pragma unroll
        for (int e = 0; e < 8; ++e) {
            float v = xb[(size_t)(cg * 16 + e) * HWP];
            s = fmaf(v, v, s); p0[e] = (f16)v;
        }
        #pragma unroll
        for (int e = 0; e < 8; ++e) {
            float v = xb[(size_t)(cg * 16 + 8 + e) * HWP];
            s = fmaf(v, v, s); p1[e] = (f16)v;
        }
        f16* o = xtg + ((size_t)(b * 8 + cg) * HWP + hw) * 16;
        *(half8*)o = p0;
        *(half8*)(o + 8) = p1;
    }
    ssq[(size_t)b * HWP + hw] = s;
}

// ---------------- precompute 2b: 3x3 box-sum of ssq -> inverse patch norm
__global__ __launch_bounds__(256)
void boxinv2_kernel(const float* __restrict__ ssq, float* __restrict__ pinv) {
    int id = blockIdx.x * 256 + threadIdx.x;
    int b = id / HWP;
    int hw = id % HWP;
    int h = hw / WW, w = hw % WW;
    const float* sb = ssq + (size_t)b * HWP;
    float S = 0.f;
    #pragma unroll
    for (int r = -1; r <= 1; ++r) {
        int hh = h + r;
        if ((unsigned)hh >= HH) continue;
        #pragma unroll
        for (int c = -1; c <= 1; ++c) {
            int ww = w + c;
            if ((unsigned)ww >= WW) continue;
            S += sb[hh * WW + ww];
        }
    }
    pinv[id] = rsqrtf(fmaxf(S, 1e-24f));
}

// ---------------- tier-A main: 2-phase pipelined (global_load_lds + dbuf + counted vmcnt)
// Block: 64 o x 2 h x 128 w; 4 waves; 16-ch chunks, tap-paired K=32.
// LDS layouts byte-identical to the R9-verified swizzled layout (conflicts = 0);
// staging sources are pre-swizzled so linear gload_lds lands data in swizzled slots.
__global__ __launch_bounds__(256, 2)
void cossim_pipe2(const f16* __restrict__ xtg, const f16* __restrict__ wng,
                  const float* __restrict__ pinv, const f16* __restrict__ zp,
                  float* __restrict__ out) {
    int bid = blockIdx.x;        // XCD-aware: b = bid&7
    int b   = bid & 7;
    int j2  = bid >> 3;
    int oy  = j2 / 56;
    int hp  = j2 % 56;
    int h0 = hp * 2;
    int o0 = oy * 64;
    int t    = threadIdx.x;
    int lane = t & 63;
    int wv   = t >> 6;

    __shared__ f16 xsb[2][8704];    // 1088 slots x 16B per buffer (1040 used + pad)
    __shared__ f16 wsb[2][10240];   // 1280 slots (1152 staged + 128 zero tap9)
    __shared__ f16 scr[512];        // dummy-DMA landing zone

    // zero pad-tap9 slots in both buffers (read every chunk, never staged)
    if (t < 128) {
        uint4 z = {0u, 0u, 0u, 0u};
        *(uint4*)&wsb[0][(1152 + t) * 8] = z;
        *(uint4*)&wsb[1][(1152 + t) * 8] = z;
    }

    // per-lane staging source offsets (chunk-invariant parts)
    int xoffk[5], woffk[5];
    #pragma unroll
    for (int k = 0; k < 5; ++k) {
        int jj = k * 4 + wv;
        int xo = -1;
        if (jj <= 16) {
            int s = jj * 64 + lane;
            if (s < 1040) {
                int po = s & 1, csm = s >> 1;
                int r = csm / 130, cs = csm - r * 130;
                int oct = po ^ ((cs >> 2) & 1);      // inverse of SWZ16
                int gh = h0 - 1 + r, gw = cs - 1;
                if ((unsigned)gh < (unsigned)HH && (unsigned)gw < (unsigned)WW)
                    xo = (gh * WW + gw) * 16 + oct * 8;
            }
        }
        xoffk[k] = xo;
        int uu = k * 4 + wv;
        int wo = -1;
        if (uu < 18) {
            int s = uu * 64 + lane;
            int tap = s >> 7, rem = s & 127, o = rem >> 1, po = rem & 1;
            int oct = po ^ ((o >> 2) & 1);
            wo = tap * 32768 + (o0 + o) * 16 + oct * 8;
        }
        woffk[k] = wo;
    }

    f32x4 acc[4][4];
    #pragma unroll
    for (int mi = 0; mi < 4; ++mi)
        #pragma unroll
        for (int ni = 0; ni < 4; ++ni) acc[mi][ni] = (f32x4){0.f, 0.f, 0.f, 0.f};

    const int lr = lane & 15;
    const int ls = lane >> 4;
    const f16* xb8 = xtg + (size_t)b * 8 * HWP * 16;

    __syncthreads();   // tap9 zeros visible before first MFMA

#define STAGE(CG, BUF) do {                                                     \
    const f16* xpl_ = xb8 + (size_t)(CG) * (HWP * 16);                          \
    const f16* wpl_ = wng + (CG) * 4096;                                        \
    _Pragma("unroll")                                                           \
    for (int k_ = 0; k_ < 5; ++k_) {                                            \
        int jj_ = k_ * 4 + wv;                                                  \
        f16* dst_ = (jj_ <= 16) ? &xsb[BUF][jj_ * 512] : scr;                   \
        const f16* src_ = (jj_ <= 16 && xoffk[k_] >= 0) ? (xpl_ + xoffk[k_])    \
                                                        : zp;                   \
        load_lds16(src_, dst_);                                                 \
    }                                                                           \
    _Pragma("unroll")                                                           \
    for (int k_ = 0; k_ < 5; ++k_) {                                            \
        int uu_ = k_ * 4 + wv;                                                  \
        f16* dst_ = (uu_ < 18) ? &wsb[BUF][uu_ * 512] : scr;                    \
        const f16* src_ = (uu_ < 18) ? (wpl_ + woffk[k_]) : zp;                 \
        load_lds16(src_, dst_);                                                 \
    }                                                                           \
} while (0)

#define PIPE_BAR() do {                                                         \
    __builtin_amdgcn_sched_barrier(0);                                          \
    __builtin_amdgcn_s_barrier();                                               \
    __builtin_amdgcn_sched_barrier(0);                                          \
} while (0)

#define MFMAP(BUF) do {                                                         \
    __builtin_amdgcn_s_setprio(1);                                              \
    _Pragma("unroll")                                                           \
    for (int p = 0; p < 5; ++p) {                                               \
        int tpl = 2 * p + (ls >> 1);                                            \
        int tpe = (tpl > 8) ? 0 : tpl;                                          \
        int kh = tpe / 3, kw = tpe - 3 * kh;                                    \
        int oct = ls & 1;                                                       \
        half8 A[4], Bf[4];                                                      \
        _Pragma("unroll")                                                       \
        for (int mi = 0; mi < 4; ++mi) {                                        \
            int row = mi * 16 + lr;                                             \
            A[mi] = *(const half8*)&wsb[BUF][                                   \
                (tpl * 128 + row * 2 + (oct ^ ((row >> 2) & 1))) * 8];          \
        }                                                                       \
        _Pragma("unroll")                                                       \
        for (int dh = 0; dh < 2; ++dh)                                          \
            _Pragma("unroll")                                                   \
            for (int wsg = 0; wsg < 2; ++wsg) {                                 \
                int col = wv * 32 + wsg * 16 + lr + kw;                         \
                Bf[dh * 2 + wsg] = *(const half8*)&xsb[BUF][                    \
                    ((dh + kh) * 260 + col * 2 + (oct ^ ((col >> 2) & 1))) * 8];\
            }                                                                   \
        _Pragma("unroll")                                                       \
        for (int mi = 0; mi < 4; ++mi)                                          \
            _Pragma("unroll")                                                   \
            for (int ni = 0; ni < 4; ++ni)                                      \
                acc[mi][ni] = __builtin_amdgcn_mfma_f32_16x16x32_f16(           \
                    A[mi], Bf[ni], acc[mi][ni], 0, 0, 0);                       \
    }                                                                           \
    __builtin_amdgcn_s_setprio(0);                                              \
} while (0)

#define ITER_MID(C) do {                                                        \
    STAGE((C) + 1, ((C) + 1) & 1);                                              \
    asm volatile("s_waitcnt vmcnt(10)" ::: "memory");                           \
    PIPE_BAR();                                                                 \
    MFMAP((C) & 1);                                                             \
    PIPE_BAR();                                                                 \
} while (0)

    STAGE(0, 0);
    ITER_MID(0);
    ITER_MID(1);
    ITER_MID(2);
    ITER_MID(3);
    ITER_MID(4);
    ITER_MID(5);
    ITER_MID(6);
    asm volatile("s_waitcnt vmcnt(0)" ::: "memory");
    PIPE_BAR();
    MFMAP(1);

#undef STAGE
#undef PIPE_BAR
#undef MFMAP
#undef ITER_MID

    // epilogue: scale by pinv (weights pre-normalized)
    int lq = lane >> 4;
    #pragma unroll
    for (int ni = 0; ni < 4; ++ni) {
        int dh = ni >> 1, wsg = ni & 1;
        int w = wv * 32 + wsg * 16 + lr;
        if (w >= WW) continue;
        float pv = pinv[(size_t)b * HWP + (h0 + dh) * WW + w];
        int h = h0 + dh;
        #pragma unroll
        for (int mi = 0; mi < 4; ++mi) {
            #pragma unroll
            for (int rg = 0; rg < 4; ++rg) {
                int row = lq * 4 + rg;
                out[((size_t)(b * OO + o0 + mi * 16 + row)) * HWP + h * WW + w]
                    = acc[mi][ni][rg] * pv;
            }
        }
    }
}

// ---------------- fallback (R4-proven) main kernel
template<int FAST>
__global__ __launch_bounds__(256, 2)
void cossim_mfma(const float* __restrict__ x, const float* __restrict__ wgt,
                 const f16* __restrict__ wn16, float* __restrict__ out) {
    int hp = blockIdx.x;
    int oy = blockIdx.y;
    int b  = blockIdx.z;
    int h0 = hp * 2;
    int o0 = oy * 64;
    int t    = threadIdx.x;
    int lane = t & 63;
    int wv   = t >> 6;

    __shared__ f16   ws[9][64][32];
    __shared__ f16   xs[4][130][32];
    __shared__ float ssqAcc[4][130];
    __shared__ float wSsq[64];
    __shared__ float pinvL[2][128];
    __shared__ float winv[64];

    for (int i = t; i < 4*130 + 64; i += 256) {
        if (i < 4*130) ((float*)ssqAcc)[i] = 0.f;
        else wSsq[i - 4*130] = 0.f;
    }
    __syncthreads();

    f32x4 zero4 = {0.f, 0.f, 0.f, 0.f};
    f32x4 acc[4][4];
    #pragma unroll
    for (int mi = 0; mi < 4; ++mi)
        #pragma unroll
        for (int ni = 0; ni < 4; ++ni) acc[mi][ni] = zero4;

    const int lr = lane & 15;
    const int ls = lane >> 4;

    for (int ch0 = 0; ch0 < E; ch0 += 32) {
        if (FAST) {
            int o = t >> 2, q = t & 3;
            #pragma unroll
            for (int r = 0; r < 9; ++r) {
                half8 v = *(const half8*)(wn16 + ((size_t)(r * OO + o0 + o)) * E + ch0 + q * 8);
                *(half8*)&ws[r][o][SWZ(q, o)] = v;
            }
        } else {
            int o = t >> 2, q = t & 3;
            const float* wrow = wgt + (size_t)(o0 + o) * 1152 + ch0 * 9 + q * 72;
            float v[72];
            float ss = 0.f;
            #pragma unroll
            for (int i = 0; i < 18; ++i) {
                float4 f = ((const float4*)wrow)[i];
                v[i*4+0] = f.x; v[i*4+1] = f.y; v[i*4+2] = f.z; v[i*4+3] = f.w;
                ss = fmaf(f.x, f.x, ss); ss = fmaf(f.y, f.y, ss);
                ss = fmaf(f.z, f.z, ss); ss = fmaf(f.w, f.w, ss);
            }
            #pragma unroll
            for (int tp = 0; tp < 9; ++tp) {
                half8 pk;
                #pragma unroll
                for (int cl = 0; cl < 8; ++cl) pk[cl] = (f16)v[cl*9 + tp];
                *(half8*)&ws[tp][o][SWZ(q, o)] = pk;
            }
            ss += __shfl_xor(ss, 1);
            ss += __shfl_xor(ss, 2);
            if (q == 0) wSsq[o] += ss;
        }
        {
            int colL = lane & 15, cq = lane >> 4;
            #pragma unroll 2
            for (int it = 0; it < 9; ++it) {
                int g = it * 4 + wv;
                int r = g / 9, colb = g % 9;
                int cs = colb * 16 + colL;
                int gh = h0 - 1 + r;
                int gw = cs - 1;
                bool okc = (cs < 130);
                bool ok  = okc && ((unsigned)gh < HH) && ((unsigned)gw < WW);
                const float* xp = x + ((size_t)b * E + ch0 + cq * 8) * HWP + gh * WW + gw;
                float vv[8];
                float ss = 0.f;
                #pragma unroll
                for (int e = 0; e < 8; ++e) {
                    float v = ok ? xp[e * HWP] : 0.f;
                    vv[e] = v;
                    ss = fmaf(v, v, ss);
                }
                if (okc) {
                    half8 pk;
                    #pragma unroll
                    for (int e = 0; e < 8; ++e) pk[e] = (f16)vv[e];
                    *(half8*)&xs[r][cs][SWZ(cq, cs)] = pk;
                }
                ss += __shfl_xor(ss, 16);
                ss += __shfl_xor(ss, 32);
                if (cq == 0 && okc) ssqAcc[r][cs] += ss;
            }
        }
        __syncthreads();

        __builtin_amdgcn_s_setprio(1);
        #pragma unroll
        for (int tap = 0; tap < 9; ++tap) {
            int kh = tap / 3, kw = tap % 3;
            half8 A[4], Bf[4];
            #pragma unroll
            for (int mi = 0; mi < 4; ++mi) {
                int row = mi * 16 + lr;
                A[mi] = *(const half8*)&ws[tap][row][SWZ(ls, row)];
            }
            #pragma unroll
            for (int dh = 0; dh < 2; ++dh)
                #pragma unroll
                for (int wsg = 0; wsg < 2; ++wsg) {
                    int col = wv * 32 + wsg * 16 + lr + kw;
                    Bf[dh*2 + wsg] = *(const half8*)&xs[dh + kh][col][SWZ(ls, col)];
                }
            #pragma unroll
            for (int mi = 0; mi < 4; ++mi)
                #pragma unroll
                for (int ni = 0; ni < 4; ++ni)
                    acc[mi][ni] = __builtin_amdgcn_mfma_f32_16x16x32_f16(
                        A[mi], Bf[ni], acc[mi][ni], 0, 0, 0);
        }
        __builtin_amdgcn_s_setprio(0);
        __syncthreads();
    }

    if (!FAST && t < 64) winv[t] = rsqrtf(fmaxf(wSsq[t], 1e-24f));
    {
        int dh = t >> 7, w = t & 127;
        float S = 0.f;
        #pragma unroll
        for (int r = 0; r < 3; ++r)
            #pragma unroll
            for (int c = 0; c < 3; ++c)
                S += ssqAcc[dh + r][w + c];
        pinvL[dh][w] = rsqrtf(fmaxf(S, 1e-24f));
    }
    __syncthreads();

    int lq = lane >> 4;
    #pragma unroll
    for (int ni = 0; ni < 4; ++ni) {
        int dh = ni >> 1, wsg = ni & 1;
        int w = wv * 32 + wsg * 16 + lr;
        if (w >= WW) continue;
        float pv = pinvL[dh][w];
        int h = h0 + dh;
        #pragma unroll
        for (int mi = 0; mi < 4; ++mi) {
            #pragma unroll
            for (int rg = 0; rg < 4; ++rg) {
                int row = lq * 4 + rg;
                float s = acc[mi][ni][rg] * pv;
                if (!FAST) s *= winv[mi*16 + row];
                out[((size_t)(b * OO + o0 + mi*16 + row)) * HWP + h * WW + w] = s;
            }
        }
    }
}

extern "C" void kernel_launch(void* const* d_in, const int* in_sizes, int n_in,
                              void* d_out, int out_size, void* d_ws, size_t ws_size,
                              hipStream_t stream) {
    const float* x   = (const float*)d_in[0];
    const float* wgt = (const float*)d_in[1];
    float* out = (float*)d_out;

    const size_t zp_b   = 1024;
    const size_t xt_b   = (size_t)BB * 8 * HWP * 16 * sizeof(f16);   // 25,690,112
    const size_t ssq_b  = (size_t)BB * HWP * sizeof(float);          // 401,408
    const size_t pinv_b = (size_t)BB * HWP * sizeof(float);          // 401,408
    const size_t wng_b  = (size_t)9 * 8 * 4096 * sizeof(f16);        // 589,824
    const size_t need_A = zp_b + xt_b + ssq_b + pinv_b + wng_b;      // 27,083,776
    const size_t wn_bytes = (size_t)9 * OO * E * sizeof(f16);        // 589,824 (fallback)

    if (ws_size >= need_A && d_ws != nullptr) {
        f16*   zp   = (f16*)d_ws;
        f16*   xtg  = (f16*)((char*)d_ws + zp_b);
        float* ssq  = (float*)((char*)d_ws + zp_b + xt_b);
        float* pinv = (float*)((char*)d_ws + zp_b + xt_b + ssq_b);
        f16*   wng  = (f16*)((char*)d_ws + zp_b + xt_b + ssq_b + pinv_b);
        xcvt2_kernel   <<<BB * (HWP / 256), 256, 0, stream>>>(x, xtg, ssq);
        wnorm16b_kernel<<<OO, 128, 0, stream>>>(wgt, wng, (float*)zp);
        boxinv2_kernel <<<BB * (HWP / 256), 256, 0, stream>>>(ssq, pinv);
        cossim_pipe2   <<<1792, 256, 0, stream>>>(xtg, wng, pinv, zp, out);
    } else if (ws_size >= wn_bytes && d_ws != nullptr) {
        f16* wn16 = (f16*)d_ws;
        wnorm16_kernel<<<OO, 128, 0, stream>>>(wgt, wn16);
        cossim_mfma<1><<<dim3(56, 4, BB), 256, 0, stream>>>(x, wgt, wn16, out);
    } else {
        cossim_mfma<0><<<dim3(56, 4, BB), 256, 0, stream>>>(x, wgt, nullptr, out);
    }
}